// Round 1
// baseline (389.530 us; speedup 1.0000x reference)
//
#include <hip/hip_runtime.h>
#include <hip/hip_bf16.h>
#include <stdint.h>

typedef __bf16 bf16_t;
typedef __bf16 bf16x8 __attribute__((ext_vector_type(8)));
typedef __bf16 bf16x4v __attribute__((ext_vector_type(4)));
typedef float f32x4 __attribute__((ext_vector_type(4)));

#define MFMA16(A, B, C) __builtin_amdgcn_mfma_f32_16x16x32_bf16((A), (B), (C), 0, 0, 0)

// Problem constants
#define BB 2
#define SS 2048
#define DD 1024
#define HH 16
#define DH 64
#define MM (BB * SS)          // 4096 rows

// ---------------- prep kernels ----------------

__global__ __launch_bounds__(256) void cvt_f32_to_bf16(const float* __restrict__ in,
                                                       bf16_t* __restrict__ out, int n4) {
  int i = blockIdx.x * blockDim.x + threadIdx.x;
  if (i >= n4) return;
  float4 v = reinterpret_cast<const float4*>(in)[i];
  bf16x4v o;
  o[0] = (bf16_t)v.x; o[1] = (bf16_t)v.y; o[2] = (bf16_t)v.z; o[3] = (bf16_t)v.w;
  reinterpret_cast<bf16x4v*>(out)[i] = o;
}

// W[K][N] (fp32) -> WT[N][K] (bf16)
__global__ void transpose_f32_to_bf16(const float* __restrict__ W, bf16_t* __restrict__ WT,
                                      int K, int N) {
  __shared__ float tile[32][33];
  int n0 = blockIdx.x * 32, k0 = blockIdx.y * 32;
  int tx = threadIdx.x, ty = threadIdx.y;
  #pragma unroll
  for (int i = ty; i < 32; i += 8) tile[i][tx] = W[(size_t)(k0 + i) * N + n0 + tx];
  __syncthreads();
  #pragma unroll
  for (int i = ty; i < 32; i += 8) WT[(size_t)(n0 + i) * K + k0 + tx] = (bf16_t)tile[tx][i];
}

// ---------------- GEMM: C[M,N] = A[M,K] * BT[N,K]^T + bias ----------------
// 128x128 tile, BK=32, 4 waves (2x2), each wave 4x4 frags of 16x16x32.
// EPI 0: QKV epilogue (scatter to q_b/k_b/vt_b bf16 + present fp32)
// EPI 1: plain fp32 output
template <int EPI>
__global__ __launch_bounds__(256) void gemm_bf16(
    const bf16_t* __restrict__ A, const bf16_t* __restrict__ BT,
    const float* __restrict__ bias, float* __restrict__ outf,
    bf16_t* __restrict__ q_b, bf16_t* __restrict__ k_b, bf16_t* __restrict__ vt_b,
    int M, int N, int K) {
  __shared__ __align__(16) bf16_t At[128 * 32];
  __shared__ __align__(16) bf16_t Bt[128 * 32];

  const int tid = threadIdx.x;
  const int l = tid & 63, w = tid >> 6;
  const int lr = l & 15, lg = l >> 4;
  const int wr = w >> 1, wc = w & 1;
  const int row0 = blockIdx.y * 128, col0 = blockIdx.x * 128;

  f32x4 vz = {0.f, 0.f, 0.f, 0.f};
  f32x4 acc[4][4];
  #pragma unroll
  for (int m = 0; m < 4; ++m)
    #pragma unroll
    for (int n = 0; n < 4; ++n) acc[m][n] = vz;

  for (int k0 = 0; k0 < K; k0 += 32) {
    __syncthreads();  // protect previous tile reads
    #pragma unroll
    for (int i = 0; i < 2; ++i) {
      int e = (tid + i * 256) * 8;  // element offset in 128x32 tile
      int r = e >> 5, c = e & 31;
      *(uint4*)&At[e] = *(const uint4*)&A[(size_t)(row0 + r) * K + k0 + c];
      *(uint4*)&Bt[e] = *(const uint4*)&BT[(size_t)(col0 + r) * K + k0 + c];
    }
    __syncthreads();
    bf16x8 af[4], bfr[4];
    #pragma unroll
    for (int m = 0; m < 4; ++m)
      af[m] = *(const bf16x8*)&At[(wr * 64 + m * 16 + lr) * 32 + lg * 8];
    #pragma unroll
    for (int n = 0; n < 4; ++n)
      bfr[n] = *(const bf16x8*)&Bt[(wc * 64 + n * 16 + lr) * 32 + lg * 8];
    #pragma unroll
    for (int m = 0; m < 4; ++m)
      #pragma unroll
      for (int n = 0; n < 4; ++n) acc[m][n] = MFMA16(af[m], bfr[n], acc[m][n]);
  }

  // epilogue: C/D layout col = lane&15, row = (lane>>4)*4 + reg
  #pragma unroll
  for (int m = 0; m < 4; ++m) {
    int rl = wr * 64 + m * 16 + lg * 4;
    #pragma unroll
    for (int n = 0; n < 4; ++n) {
      int col = col0 + wc * 64 + n * 16 + lr;
      float bz = bias[col];
      #pragma unroll
      for (int r = 0; r < 4; ++r) {
        int row = row0 + rl + r;
        float v = acc[m][n][r] + bz;
        if (EPI == 1) {
          outf[(size_t)row * N + col] = v;
        } else {
          int b = row >> 11, s = row & 2047;
          int part = col >> 10, d = col & 1023;
          int h = d >> 6, dh = d & 63;
          size_t idx = ((size_t)(b * HH + h) * SS + s) * DH + dh;
          if (part == 0) {
            q_b[idx] = (bf16_t)v;
          } else if (part == 1) {
            k_b[idx] = (bf16_t)v;
            outf[(((size_t)(b * 2 + 0) * HH + h) * SS + s) * DH + dh] = v;  // present K
          } else {
            vt_b[((size_t)(b * HH + h) * DH + dh) * SS + s] = (bf16_t)v;   // V transposed
            outf[(((size_t)(b * 2 + 1) * HH + h) * SS + s) * DH + dh] = v;  // present V
          }
        }
      }
    }
  }
}

// ---------------- flash attention ----------------
// grid: x = S/64 q-tiles, y = B*H. 4 independent waves, each owns 16 q rows.
// Swapped QK^T: S^T = mfma(K_frag, Q^T_frag) -> lane col = q, row = kv.
__global__ __launch_bounds__(256) void attn_fwd(
    const bf16_t* __restrict__ q_b, const bf16_t* __restrict__ k_b,
    const bf16_t* __restrict__ vt_b, bf16_t* __restrict__ attn_out) {
  const int bh = blockIdx.y;
  const int q0 = blockIdx.x * 64;
  const int tid = threadIdx.x;
  const int w = tid >> 6, l = tid & 63;
  const int lr = l & 15, lg = l >> 4;

  __shared__ __align__(16) bf16_t P_lds[4][16][72];  // [wave][q_local][kv], +8 pad

  const bf16_t* qb = q_b + (size_t)bh * SS * DH;
  const bf16_t* kb = k_b + (size_t)bh * SS * DH;
  const bf16_t* vt = vt_b + (size_t)bh * DH * SS;

  const int qrow = q0 + w * 16 + lr;  // this lane's q (B-frag col)
  bf16x8 qf0 = *(const bf16x8*)&qb[(size_t)qrow * DH + lg * 8];
  bf16x8 qf1 = *(const bf16x8*)&qb[(size_t)qrow * DH + 32 + lg * 8];

  f32x4 vzero = {0.f, 0.f, 0.f, 0.f};
  f32x4 oacc[4];
  #pragma unroll
  for (int d = 0; d < 4; ++d) oacc[d] = vzero;
  float m_run = -1e30f, l_run = 0.f;

  const int nkv = q0 / 64 + 1;  // causal: only tiles with kv0 <= q0
  for (int t = 0; t < nkv; ++t) {
    const int kvt = t * 64;
    // ---- QK^T (swapped) ----
    float sc[4][4];
    #pragma unroll
    for (int kvf = 0; kvf < 4; ++kvf) {
      int kvr = kvt + kvf * 16 + lr;  // A-frag row = kv
      bf16x8 kf0 = *(const bf16x8*)&kb[(size_t)kvr * DH + lg * 8];
      bf16x8 kf1 = *(const bf16x8*)&kb[(size_t)kvr * DH + 32 + lg * 8];
      f32x4 a = vzero;
      a = MFMA16(kf0, qf0, a);
      a = MFMA16(kf1, qf1, a);
      #pragma unroll
      for (int r = 0; r < 4; ++r) {
        int kv = kvt + kvf * 16 + lg * 4 + r;  // D row = kv
        float s = a[r] * 0.125f;               // 1/sqrt(64)
        sc[kvf][r] = (kv > qrow) ? -1e10f : s; // causal mask, matches ref constant
      }
    }
    // ---- online softmax (row = q = lane&15; reduce across lane^16, lane^32) ----
    float tmax = -1e30f;
    #pragma unroll
    for (int kvf = 0; kvf < 4; ++kvf)
      #pragma unroll
      for (int r = 0; r < 4; ++r) tmax = fmaxf(tmax, sc[kvf][r]);
    tmax = fmaxf(tmax, __shfl_xor(tmax, 16));
    tmax = fmaxf(tmax, __shfl_xor(tmax, 32));
    float mnew = fmaxf(m_run, tmax);
    float alpha = __expf(m_run - mnew);
    float psum = 0.f;
    #pragma unroll
    for (int kvf = 0; kvf < 4; ++kvf)
      #pragma unroll
      for (int r = 0; r < 4; ++r) {
        float p = __expf(sc[kvf][r] - mnew);
        sc[kvf][r] = p;
        psum += p;
      }
    psum += __shfl_xor(psum, 16);
    psum += __shfl_xor(psum, 32);
    l_run = l_run * alpha + psum;
    m_run = mnew;
    #pragma unroll
    for (int d = 0; d < 4; ++d) oacc[d] *= alpha;
    // ---- P -> LDS (bf16), [q][kv] so PV B-frag is contiguous ----
    #pragma unroll
    for (int kvf = 0; kvf < 4; ++kvf) {
      bf16x4v pk;
      #pragma unroll
      for (int r = 0; r < 4; ++r) pk[r] = (bf16_t)sc[kvf][r];
      *(bf16x4v*)&P_lds[w][lr][kvf * 16 + lg * 4] = pk;
    }
    // same-wave LDS RAW: compiler inserts lgkmcnt waits; no barrier needed
    // ---- PV: O^T[d][q] += V^T[d][kv] * P^T[kv][q] ----
    #pragma unroll
    for (int d = 0; d < 4; ++d) {
      const bf16_t* vrow = &vt[(size_t)(d * 16 + lr) * SS + kvt];
      bf16x8 vf0 = *(const bf16x8*)&vrow[lg * 8];
      bf16x8 vf1 = *(const bf16x8*)&vrow[32 + lg * 8];
      bf16x8 pf0 = *(const bf16x8*)&P_lds[w][lr][lg * 8];
      bf16x8 pf1 = *(const bf16x8*)&P_lds[w][lr][32 + lg * 8];
      oacc[d] = MFMA16(vf0, pf0, oacc[d]);
      oacc[d] = MFMA16(vf1, pf1, oacc[d]);
    }
  }
  // ---- epilogue: merge heads into [B*S, D] bf16 ----
  const int b = bh >> 4, h = bh & 15;
  float inv_l = 1.f / l_run;
  #pragma unroll
  for (int d = 0; d < 4; ++d)
    #pragma unroll
    for (int r = 0; r < 4; ++r) {
      int dd = d * 16 + lg * 4 + r;
      attn_out[((size_t)(b * SS + qrow)) * DD + h * DH + dd] = (bf16_t)(oacc[d][r] * inv_l);
    }
}

// ---------------- launcher ----------------
extern "C" void kernel_launch(void* const* d_in, const int* in_sizes, int n_in,
                              void* d_out, int out_size, void* d_ws, size_t ws_size,
                              hipStream_t stream) {
  const float* x = (const float*)d_in[0];
  const float* c_attn_w = (const float*)d_in[1];
  const float* c_attn_b = (const float*)d_in[2];
  const float* c_proj_w = (const float*)d_in[3];
  const float* c_proj_b = (const float*)d_in[4];

  float* out = (float*)d_out;                       // a: [B,S,D]
  float* present = out + (size_t)BB * SS * DD;      // present: [B,2,H,S,Dh]

  char* ws = (char*)d_ws;
  bf16_t* xb     = (bf16_t*)(ws + 0);               //  8.4 MB  x as bf16 [M,K]
  bf16_t* wqkvT  = (bf16_t*)(ws + 8388608);         //  6.3 MB  [3072,1024]
  bf16_t* wprojT = (bf16_t*)(ws + 14680064);        //  2.1 MB  [1024,1024]
  bf16_t* q_b    = (bf16_t*)(ws + 16777216);        //  8.4 MB  [B,H,S,64]
  bf16_t* k_b    = (bf16_t*)(ws + 25165824);        //  8.4 MB  [B,H,S,64]
  bf16_t* vt_b   = (bf16_t*)(ws + 33554432);        //  8.4 MB  [B,H,64,S]
  bf16_t* attn_o = (bf16_t*)(ws + 41943040);        //  8.4 MB  [M,D]

  // 1. x -> bf16
  cvt_f32_to_bf16<<<(MM * DD / 4 + 255) / 256, 256, 0, stream>>>(x, xb, MM * DD / 4);
  // 2. weight transposes
  transpose_f32_to_bf16<<<dim3(3 * DD / 32, DD / 32), dim3(32, 8), 0, stream>>>(
      c_attn_w, wqkvT, DD, 3 * DD);
  transpose_f32_to_bf16<<<dim3(DD / 32, DD / 32), dim3(32, 8), 0, stream>>>(
      c_proj_w, wprojT, DD, DD);
  // 3. QKV GEMM [4096,1024]x[1024,3072] with scatter epilogue
  gemm_bf16<0><<<dim3(3 * DD / 128, MM / 128), 256, 0, stream>>>(
      xb, wqkvT, c_attn_b, present, q_b, k_b, vt_b, MM, 3 * DD, DD);
  // 4. flash attention
  attn_fwd<<<dim3(SS / 64, BB * HH), 256, 0, stream>>>(q_b, k_b, vt_b, attn_o);
  // 5. output projection [4096,1024]x[1024,1024]
  gemm_bf16<1><<<dim3(DD / 128, MM / 128), 256, 0, stream>>>(
      attn_o, wprojT, c_proj_b, out, nullptr, nullptr, nullptr, MM, DD, DD);
}

// Round 2
// 246.173 us; speedup vs baseline: 1.5823x; 1.5823x over previous
//
#include <hip/hip_runtime.h>
#include <hip/hip_bf16.h>
#include <stdint.h>

typedef __bf16 bf16_t;
typedef __bf16 bf16x8 __attribute__((ext_vector_type(8)));
typedef __bf16 bf16x4v __attribute__((ext_vector_type(4)));
typedef float f32x4 __attribute__((ext_vector_type(4)));

#define MFMA16(A, B, C) __builtin_amdgcn_mfma_f32_16x16x32_bf16((A), (B), (C), 0, 0, 0)

// Problem constants
#define BB 2
#define SS 2048
#define DD 1024
#define HH 16
#define DH 64
#define MM (BB * SS)          // 4096 rows

// async global->LDS, 16B per lane. LDS dest must be wave-uniform base
// (HW adds lane*16); global src is per-lane.
__device__ __forceinline__ void load_lds16(const void* g, void* l) {
  __builtin_amdgcn_global_load_lds(
      (const __attribute__((address_space(1))) void*)g,
      (__attribute__((address_space(3))) void*)l, 16, 0, 0);
}

// ---------------- prep kernels ----------------

__global__ __launch_bounds__(256) void cvt_f32_to_bf16(const float* __restrict__ in,
                                                       bf16_t* __restrict__ out, int n4) {
  int i = blockIdx.x * blockDim.x + threadIdx.x;
  if (i >= n4) return;
  float4 v = reinterpret_cast<const float4*>(in)[i];
  bf16x4v o;
  o[0] = (bf16_t)v.x; o[1] = (bf16_t)v.y; o[2] = (bf16_t)v.z; o[3] = (bf16_t)v.w;
  reinterpret_cast<bf16x4v*>(out)[i] = o;
}

// W[K][N] (fp32) -> WT[N][K] (bf16)
__global__ void transpose_f32_to_bf16(const float* __restrict__ W, bf16_t* __restrict__ WT,
                                      int K, int N) {
  __shared__ float tile[32][33];
  int n0 = blockIdx.x * 32, k0 = blockIdx.y * 32;
  int tx = threadIdx.x, ty = threadIdx.y;
  #pragma unroll
  for (int i = ty; i < 32; i += 8) tile[i][tx] = W[(size_t)(k0 + i) * N + n0 + tx];
  __syncthreads();
  #pragma unroll
  for (int i = ty; i < 32; i += 8) WT[(size_t)(n0 + i) * K + k0 + tx] = (bf16_t)tile[tx][i];
}

// ---------------- GEMM: C[M,N] = A[M,K] * BT[N,K]^T + bias ----------------
// 128x128 tile, BK=32, 4 waves (2x2), each wave 4x4 frags of 16x16x32.
// Staging via global_load_lds width=16 (m97 pattern), linear LDS layout.
template <int EPI>
__global__ __launch_bounds__(256) void gemm_bf16(
    const bf16_t* __restrict__ A, const bf16_t* __restrict__ BT,
    const float* __restrict__ bias, float* __restrict__ outf,
    bf16_t* __restrict__ q_b, bf16_t* __restrict__ k_b, bf16_t* __restrict__ vt_b,
    int M, int N, int K) {
  __shared__ __align__(16) bf16_t At[128 * 32];
  __shared__ __align__(16) bf16_t Bt[128 * 32];

  const int tid = threadIdx.x;
  const int l = tid & 63, w = tid >> 6;
  const int lr = l & 15, lg = l >> 4;
  const int wr = w >> 1, wc = w & 1;
  const int row0 = blockIdx.y * 128, col0 = blockIdx.x * 128;

  f32x4 vz = {0.f, 0.f, 0.f, 0.f};
  f32x4 acc[4][4];
  #pragma unroll
  for (int m = 0; m < 4; ++m)
    #pragma unroll
    for (int n = 0; n < 4; ++n) acc[m][n] = vz;

  for (int k0 = 0; k0 < K; k0 += 32) {
    __syncthreads();  // previous tile fully consumed
    #pragma unroll
    for (int i = 0; i < 2; ++i) {
      int e = (tid + i * 256) * 8;  // element offset in 128x32 tile
      int r = e >> 5, c = e & 31;
      int base = (w * 64 + i * 256) * 8;  // wave-uniform LDS dest (elements)
      load_lds16(&A[(size_t)(row0 + r) * K + k0 + c], &At[base]);
      load_lds16(&BT[(size_t)(col0 + r) * K + k0 + c], &Bt[base]);
    }
    __syncthreads();  // compiler emits vmcnt(0) before barrier -> staged
    bf16x8 af[4], bfr[4];
    #pragma unroll
    for (int m = 0; m < 4; ++m)
      af[m] = *(const bf16x8*)&At[(wr * 64 + m * 16 + lr) * 32 + lg * 8];
    #pragma unroll
    for (int n = 0; n < 4; ++n)
      bfr[n] = *(const bf16x8*)&Bt[(wc * 64 + n * 16 + lr) * 32 + lg * 8];
    #pragma unroll
    for (int m = 0; m < 4; ++m)
      #pragma unroll
      for (int n = 0; n < 4; ++n) acc[m][n] = MFMA16(af[m], bfr[n], acc[m][n]);
  }

  // epilogue: C/D layout col = lane&15, row = (lane>>4)*4 + reg
  #pragma unroll
  for (int m = 0; m < 4; ++m) {
    int rl = wr * 64 + m * 16 + lg * 4;
    #pragma unroll
    for (int n = 0; n < 4; ++n) {
      int col = col0 + wc * 64 + n * 16 + lr;
      float bz = bias[col];
      #pragma unroll
      for (int r = 0; r < 4; ++r) {
        int row = row0 + rl + r;
        float v = acc[m][n][r] + bz;
        if (EPI == 1) {
          outf[(size_t)row * N + col] = v;
        } else {
          int b = row >> 11, s = row & 2047;
          int part = col >> 10, d = col & 1023;
          int h = d >> 6, dh = d & 63;
          size_t idx = ((size_t)(b * HH + h) * SS + s) * DH + dh;
          if (part == 0) {
            q_b[idx] = (bf16_t)v;
          } else if (part == 1) {
            k_b[idx] = (bf16_t)v;
            outf[(((size_t)(b * 2 + 0) * HH + h) * SS + s) * DH + dh] = v;  // present K
          } else {
            vt_b[((size_t)(b * HH + h) * DH + dh) * SS + s] = (bf16_t)v;   // V transposed
            outf[(((size_t)(b * 2 + 1) * HH + h) * SS + s) * DH + dh] = v;  // present V
          }
        }
      }
    }
  }
}

// ---------------- flash attention ----------------
// grid: x = S/128 q-bands (reversed: longest first), y = B*H.
// 4 waves; each wave owns 32 q rows (2 q-frags). K,V^T tiles (64x64) staged
// once per block in LDS via global_load_lds: linear LDS dest, XOR-swizzled
// global source; reads apply the same XOR (m173/m201 pattern).
__global__ __launch_bounds__(256) void attn_fwd(
    const bf16_t* __restrict__ q_b, const bf16_t* __restrict__ k_b,
    const bf16_t* __restrict__ vt_b, bf16_t* __restrict__ attn_out) {
  __shared__ __align__(16) bf16_t Kt[64 * 64];           // [kv][d] 8KB
  __shared__ __align__(16) bf16_t Vt[64 * 64];           // [d][kv] 8KB
  __shared__ __align__(16) bf16_t P_lds[4][32][72];      // [wave][q][kv]+pad 18KB

  const int bh = blockIdx.y;
  const int q0b = (gridDim.x - 1 - blockIdx.x) * 128;    // reversed launch order
  const int tid = threadIdx.x;
  const int w = tid >> 6, l = tid & 63;
  const int lr = l & 15, lg = l >> 4;

  const bf16_t* qb = q_b + (size_t)bh * SS * DH;
  const bf16_t* kb = k_b + (size_t)bh * SS * DH;
  const bf16_t* vt = vt_b + (size_t)bh * DH * SS;

  const int qrow0 = q0b + w * 32 + lr;  // q-frag 0
  const int qrow1 = qrow0 + 16;         // q-frag 1
  bf16x8 qf[2][2];
  qf[0][0] = *(const bf16x8*)&qb[(size_t)qrow0 * DH + lg * 8];
  qf[0][1] = *(const bf16x8*)&qb[(size_t)qrow0 * DH + 32 + lg * 8];
  qf[1][0] = *(const bf16x8*)&qb[(size_t)qrow1 * DH + lg * 8];
  qf[1][1] = *(const bf16x8*)&qb[(size_t)qrow1 * DH + 32 + lg * 8];

  f32x4 vzero = {0.f, 0.f, 0.f, 0.f};
  f32x4 oacc[2][4];
  #pragma unroll
  for (int q = 0; q < 2; ++q)
    #pragma unroll
    for (int d = 0; d < 4; ++d) oacc[q][d] = vzero;
  float m_run[2] = {-1e30f, -1e30f}, l_run[2] = {0.f, 0.f};

  const int nkv = q0b / 64 + 2;  // covers block's q band [q0b, q0b+128)
  for (int t = 0; t < nkv; ++t) {
    const int kv0 = t * 64;
    // ---- stage K[kv][d] and V^T[d][kv] tiles; src pre-swizzled, dest linear
    #pragma unroll
    for (int i = 0; i < 2; ++i) {
      int e = (tid + i * 256) * 8;                 // element in 64x64 tile
      int r = e >> 6;                              // tile row
      int cs = (((e & 63) * 2) ^ ((r & 7) << 4)) >> 1;  // swizzled src col (elems)
      int base = (w * 64 + i * 256) * 8;           // wave-uniform LDS dest
      load_lds16(&kb[(size_t)(kv0 + r) * DH + cs], &Kt[base]);
      load_lds16(&vt[(size_t)r * SS + kv0 + cs], &Vt[base]);
    }
    __syncthreads();

    // ---- QK^T (swapped): lane col = q, D-row = kv ----
    float sc[2][4][4];
    #pragma unroll
    for (int kvf = 0; kvf < 4; ++kvf) {
      int rr = kvf * 16 + lr;
      int sw = (rr & 7) << 4;
      bf16x8 kf0 = *(const bf16x8*)((const char*)Kt + rr * 128 + ((lg * 16) ^ sw));
      bf16x8 kf1 = *(const bf16x8*)((const char*)Kt + rr * 128 + ((64 + lg * 16) ^ sw));
      #pragma unroll
      for (int q = 0; q < 2; ++q) {
        f32x4 a = vzero;
        a = MFMA16(kf0, qf[q][0], a);
        a = MFMA16(kf1, qf[q][1], a);
        int qrow = q ? qrow1 : qrow0;
        #pragma unroll
        for (int r = 0; r < 4; ++r) {
          int kv = kv0 + kvf * 16 + lg * 4 + r;
          float s = a[r] * 0.125f;                // 1/sqrt(64)
          sc[q][kvf][r] = (kv > qrow) ? -1e10f : s;
        }
      }
    }

    // ---- online softmax per q-frag (row = q = lane&15) ----
    #pragma unroll
    for (int q = 0; q < 2; ++q) {
      float tmax = -1e30f;
      #pragma unroll
      for (int kvf = 0; kvf < 4; ++kvf)
        #pragma unroll
        for (int r = 0; r < 4; ++r) tmax = fmaxf(tmax, sc[q][kvf][r]);
      tmax = fmaxf(tmax, __shfl_xor(tmax, 16));
      tmax = fmaxf(tmax, __shfl_xor(tmax, 32));
      float mnew = fmaxf(m_run[q], tmax);
      float alpha = __expf(m_run[q] - mnew);
      float psum = 0.f;
      #pragma unroll
      for (int kvf = 0; kvf < 4; ++kvf)
        #pragma unroll
        for (int r = 0; r < 4; ++r) {
          float p = __expf(sc[q][kvf][r] - mnew);
          sc[q][kvf][r] = p;
          psum += p;
        }
      psum += __shfl_xor(psum, 16);
      psum += __shfl_xor(psum, 32);
      l_run[q] = l_run[q] * alpha + psum;
      m_run[q] = mnew;
      #pragma unroll
      for (int d = 0; d < 4; ++d) oacc[q][d] *= alpha;
      #pragma unroll
      for (int kvf = 0; kvf < 4; ++kvf) {
        bf16x4v pk;
        #pragma unroll
        for (int r = 0; r < 4; ++r) pk[r] = (bf16_t)sc[q][kvf][r];
        *(bf16x4v*)&P_lds[w][q * 16 + lr][kvf * 16 + lg * 4] = pk;
      }
    }
    // same-wave LDS RAW -> compiler lgkmcnt waits; no barrier needed

    // ---- PV: O^T[d][q] += V^T[d][kv] * P^T[kv][q] ----
    bf16x8 pf[2][2];
    #pragma unroll
    for (int q = 0; q < 2; ++q) {
      pf[q][0] = *(const bf16x8*)&P_lds[w][q * 16 + lr][lg * 8];
      pf[q][1] = *(const bf16x8*)&P_lds[w][q * 16 + lr][32 + lg * 8];
    }
    #pragma unroll
    for (int d = 0; d < 4; ++d) {
      int dl = d * 16 + lr;
      int sw = (dl & 7) << 4;
      bf16x8 vf0 = *(const bf16x8*)((const char*)Vt + dl * 128 + ((lg * 16) ^ sw));
      bf16x8 vf1 = *(const bf16x8*)((const char*)Vt + dl * 128 + ((64 + lg * 16) ^ sw));
      #pragma unroll
      for (int q = 0; q < 2; ++q) {
        oacc[q][d] = MFMA16(vf0, pf[q][0], oacc[q][d]);
        oacc[q][d] = MFMA16(vf1, pf[q][1], oacc[q][d]);
      }
    }
    __syncthreads();  // all waves done reading Kt/Vt before next stage
  }

  // ---- epilogue: merge heads into [B*S, D] bf16 ----
  const int b = bh >> 4, h = bh & 15;
  #pragma unroll
  for (int q = 0; q < 2; ++q) {
    float inv_l = 1.f / l_run[q];
    int qrow = q ? qrow1 : qrow0;
    #pragma unroll
    for (int d = 0; d < 4; ++d)
      #pragma unroll
      for (int r = 0; r < 4; ++r) {
        int dd = d * 16 + lg * 4 + r;
        attn_out[((size_t)(b * SS + qrow)) * DD + h * DH + dd] =
            (bf16_t)(oacc[q][d][r] * inv_l);
      }
  }
}

// ---------------- launcher ----------------
extern "C" void kernel_launch(void* const* d_in, const int* in_sizes, int n_in,
                              void* d_out, int out_size, void* d_ws, size_t ws_size,
                              hipStream_t stream) {
  const float* x = (const float*)d_in[0];
  const float* c_attn_w = (const float*)d_in[1];
  const float* c_attn_b = (const float*)d_in[2];
  const float* c_proj_w = (const float*)d_in[3];
  const float* c_proj_b = (const float*)d_in[4];

  float* out = (float*)d_out;                       // a: [B,S,D]
  float* present = out + (size_t)BB * SS * DD;      // present: [B,2,H,S,Dh]

  char* ws = (char*)d_ws;
  bf16_t* xb     = (bf16_t*)(ws + 0);               //  8.4 MB  x as bf16 [M,K]
  bf16_t* wqkvT  = (bf16_t*)(ws + 8388608);         //  6.3 MB  [3072,1024]
  bf16_t* wprojT = (bf16_t*)(ws + 14680064);        //  2.1 MB  [1024,1024]
  bf16_t* q_b    = (bf16_t*)(ws + 16777216);        //  8.4 MB  [B,H,S,64]
  bf16_t* k_b    = (bf16_t*)(ws + 25165824);        //  8.4 MB  [B,H,S,64]
  bf16_t* vt_b   = (bf16_t*)(ws + 33554432);        //  8.4 MB  [B,H,64,S]
  bf16_t* attn_o = (bf16_t*)(ws + 41943040);        //  8.4 MB  [M,D]

  // 1. x -> bf16
  cvt_f32_to_bf16<<<(MM * DD / 4 + 255) / 256, 256, 0, stream>>>(x, xb, MM * DD / 4);
  // 2. weight transposes
  transpose_f32_to_bf16<<<dim3(3 * DD / 32, DD / 32), dim3(32, 8), 0, stream>>>(
      c_attn_w, wqkvT, DD, 3 * DD);
  transpose_f32_to_bf16<<<dim3(DD / 32, DD / 32), dim3(32, 8), 0, stream>>>(
      c_proj_w, wprojT, DD, DD);
  // 3. QKV GEMM [4096,1024]x[1024,3072] with scatter epilogue
  gemm_bf16<0><<<dim3(3 * DD / 128, MM / 128), 256, 0, stream>>>(
      xb, wqkvT, c_attn_b, present, q_b, k_b, vt_b, MM, 3 * DD, DD);
  // 4. flash attention
  attn_fwd<<<dim3(SS / 128, BB * HH), 256, 0, stream>>>(q_b, k_b, vt_b, attn_o);
  // 5. output projection [4096,1024]x[1024,1024]
  gemm_bf16<1><<<dim3(DD / 128, MM / 128), 256, 0, stream>>>(
      attn_o, wprojT, c_proj_b, out, nullptr, nullptr, nullptr, MM, DD, DD);
}

// Round 3
// 245.418 us; speedup vs baseline: 1.5872x; 1.0031x over previous
//
#include <hip/hip_runtime.h>
#include <hip/hip_bf16.h>
#include <stdint.h>

typedef __bf16 bf16_t;
typedef __bf16 bf16x8 __attribute__((ext_vector_type(8)));
typedef __bf16 bf16x4v __attribute__((ext_vector_type(4)));
typedef float f32x4 __attribute__((ext_vector_type(4)));

#define MFMA16(A, B, C) __builtin_amdgcn_mfma_f32_16x16x32_bf16((A), (B), (C), 0, 0, 0)

// Problem constants
#define BB 2
#define SS 2048
#define DD 1024
#define HH 16
#define DH 64
#define MM (BB * SS)          // 4096 rows

// async global->LDS, 16B per lane. LDS dest must be wave-uniform base
// (HW adds lane*16); global src is per-lane.
__device__ __forceinline__ void load_lds16(const void* g, void* l) {
  __builtin_amdgcn_global_load_lds(
      (const __attribute__((address_space(1))) void*)g,
      (__attribute__((address_space(3))) void*)l, 16, 0, 0);
}

// ---------------- prep kernels ----------------

__global__ __launch_bounds__(256) void cvt_f32_to_bf16(const float* __restrict__ in,
                                                       bf16_t* __restrict__ out, int n4) {
  int i = blockIdx.x * blockDim.x + threadIdx.x;
  if (i >= n4) return;
  float4 v = reinterpret_cast<const float4*>(in)[i];
  bf16x4v o;
  o[0] = (bf16_t)v.x; o[1] = (bf16_t)v.y; o[2] = (bf16_t)v.z; o[3] = (bf16_t)v.w;
  reinterpret_cast<bf16x4v*>(out)[i] = o;
}

// W[K][N] (fp32) -> WT[N][K] (bf16)
__global__ void transpose_f32_to_bf16(const float* __restrict__ W, bf16_t* __restrict__ WT,
                                      int K, int N) {
  __shared__ float tile[32][33];
  int n0 = blockIdx.x * 32, k0 = blockIdx.y * 32;
  int tx = threadIdx.x, ty = threadIdx.y;
  #pragma unroll
  for (int i = ty; i < 32; i += 8) tile[i][tx] = W[(size_t)(k0 + i) * N + n0 + tx];
  __syncthreads();
  #pragma unroll
  for (int i = ty; i < 32; i += 8) WT[(size_t)(n0 + i) * K + k0 + tx] = (bf16_t)tile[tx][i];
}

// ---------------- GEMM: C[M,N] = A[M,K] * BT[N,K]^T + bias ----------------
// 128x128 tile, BK=32, 4 waves (2x2), each wave 4x4 frags of 16x16x32.
// 2-phase double-buffered prefetch (T3 minimum): STAGE(next) before compute,
// ONE barrier per K-step -> load latency hides under MFMA.
template <int EPI>
__global__ __launch_bounds__(256) void gemm_bf16(
    const bf16_t* __restrict__ A, const bf16_t* __restrict__ BT,
    const float* __restrict__ bias, float* __restrict__ outf,
    bf16_t* __restrict__ q_b, bf16_t* __restrict__ k_b, bf16_t* __restrict__ vt_b,
    int M, int N, int K) {
  __shared__ __align__(16) bf16_t At[2][128 * 32];
  __shared__ __align__(16) bf16_t Bt[2][128 * 32];

  const int tid = threadIdx.x;
  const int l = tid & 63, w = tid >> 6;
  const int lr = l & 15, lg = l >> 4;
  const int wr = w >> 1, wc = w & 1;
  const int row0 = blockIdx.y * 128, col0 = blockIdx.x * 128;

  auto stage = [&](int buf, int k0) {
    #pragma unroll
    for (int i = 0; i < 2; ++i) {
      int e = (tid + i * 256) * 8;  // element offset in 128x32 tile
      int r = e >> 5, c = e & 31;
      int base = (w * 64 + i * 256) * 8;  // wave-uniform LDS dest (elements)
      load_lds16(&A[(size_t)(row0 + r) * K + k0 + c], &At[buf][base]);
      load_lds16(&BT[(size_t)(col0 + r) * K + k0 + c], &Bt[buf][base]);
    }
  };

  f32x4 vz = {0.f, 0.f, 0.f, 0.f};
  f32x4 acc[4][4];
  #pragma unroll
  for (int m = 0; m < 4; ++m)
    #pragma unroll
    for (int n = 0; n < 4; ++n) acc[m][n] = vz;

  stage(0, 0);
  __syncthreads();  // vmcnt(0) drain: buf0 ready
  int cur = 0;
  for (int k0 = 0; k0 < K; k0 += 32) {
    if (k0 + 32 < K) stage(cur ^ 1, k0 + 32);  // prefetch next K-tile
    bf16x8 af[4], bfr[4];
    #pragma unroll
    for (int m = 0; m < 4; ++m)
      af[m] = *(const bf16x8*)&At[cur][(wr * 64 + m * 16 + lr) * 32 + lg * 8];
    #pragma unroll
    for (int n = 0; n < 4; ++n)
      bfr[n] = *(const bf16x8*)&Bt[cur][(wc * 64 + n * 16 + lr) * 32 + lg * 8];
    #pragma unroll
    for (int m = 0; m < 4; ++m)
      #pragma unroll
      for (int n = 0; n < 4; ++n) acc[m][n] = MFMA16(af[m], bfr[n], acc[m][n]);
    __syncthreads();  // drains prefetch (flew during compute) + read-safety
    cur ^= 1;
  }

  // epilogue: C/D layout col = lane&15, row = (lane>>4)*4 + reg
  #pragma unroll
  for (int m = 0; m < 4; ++m) {
    int rl = wr * 64 + m * 16 + lg * 4;
    #pragma unroll
    for (int n = 0; n < 4; ++n) {
      int col = col0 + wc * 64 + n * 16 + lr;
      float bz = bias[col];
      #pragma unroll
      for (int r = 0; r < 4; ++r) {
        int row = row0 + rl + r;
        float v = acc[m][n][r] + bz;
        if (EPI == 1) {
          outf[(size_t)row * N + col] = v;
        } else {
          int b = row >> 11, s = row & 2047;
          int part = col >> 10, d = col & 1023;
          int h = d >> 6, dh = d & 63;
          size_t idx = ((size_t)(b * HH + h) * SS + s) * DH + dh;
          if (part == 0) {
            q_b[idx] = (bf16_t)v;
          } else if (part == 1) {
            k_b[idx] = (bf16_t)v;
            outf[(((size_t)(b * 2 + 0) * HH + h) * SS + s) * DH + dh] = v;  // present K
          } else {
            vt_b[((size_t)(b * HH + h) * DH + dh) * SS + s] = (bf16_t)v;   // V transposed
            outf[(((size_t)(b * 2 + 1) * HH + h) * SS + s) * DH + dh] = v;  // present V
          }
        }
      }
    }
  }
}

// ---------------- flash attention ----------------
// grid: x = S/128 q-bands (reversed: longest first), y = B*H.
// 4 waves; each wave owns 32 q rows (2 q-frags). K,V^T tiles (64x64)
// double-buffered in LDS, prefetched one tile ahead (2-phase pipeline).
// log2-domain softmax (exp2), defer-max THR=8, mask-skip on interior tiles.
__global__ __launch_bounds__(256) void attn_fwd(
    const bf16_t* __restrict__ q_b, const bf16_t* __restrict__ k_b,
    const bf16_t* __restrict__ vt_b, bf16_t* __restrict__ attn_out) {
  __shared__ __align__(16) bf16_t Kt[2][64 * 64];        // [kv][d] 2x8KB
  __shared__ __align__(16) bf16_t Vt[2][64 * 64];        // [d][kv] 2x8KB
  __shared__ __align__(16) bf16_t P_lds[4][32][72];      // [wave][q][kv]+pad 18KB

  const int bh = blockIdx.y;
  const int q0b = (gridDim.x - 1 - blockIdx.x) * 128;    // reversed launch order
  const int tid = threadIdx.x;
  const int w = tid >> 6, l = tid & 63;
  const int lr = l & 15, lg = l >> 4;

  const bf16_t* qb = q_b + (size_t)bh * SS * DH;
  const bf16_t* kb = k_b + (size_t)bh * SS * DH;
  const bf16_t* vt = vt_b + (size_t)bh * DH * SS;

  auto stageKV = [&](int buf, int kv0) {
    #pragma unroll
    for (int i = 0; i < 2; ++i) {
      int e = (tid + i * 256) * 8;                 // element in 64x64 tile
      int r = e >> 6;                              // tile row
      int cs = (((e & 63) * 2) ^ ((r & 7) << 4)) >> 1;  // swizzled src col (elems)
      int base = (w * 64 + i * 256) * 8;           // wave-uniform LDS dest
      load_lds16(&kb[(size_t)(kv0 + r) * DH + cs], &Kt[buf][base]);
      load_lds16(&vt[(size_t)r * SS + kv0 + cs], &Vt[buf][base]);
    }
  };

  const int qrow0 = q0b + w * 32 + lr;  // q-frag 0
  const int qrow1 = qrow0 + 16;         // q-frag 1
  bf16x8 qf[2][2];
  qf[0][0] = *(const bf16x8*)&qb[(size_t)qrow0 * DH + lg * 8];
  qf[0][1] = *(const bf16x8*)&qb[(size_t)qrow0 * DH + 32 + lg * 8];
  qf[1][0] = *(const bf16x8*)&qb[(size_t)qrow1 * DH + lg * 8];
  qf[1][1] = *(const bf16x8*)&qb[(size_t)qrow1 * DH + 32 + lg * 8];

  f32x4 vzero = {0.f, 0.f, 0.f, 0.f};
  f32x4 oacc[2][4];
  #pragma unroll
  for (int q = 0; q < 2; ++q)
    #pragma unroll
    for (int d = 0; d < 4; ++d) oacc[q][d] = vzero;
  float m_run[2] = {-1e30f, -1e30f}, l_run[2] = {0.f, 0.f};

  const float SCL = 0.125f * 1.4426950408889634f;  // fold 1/sqrt(64) * log2(e)

  const int nkv = q0b / 64 + 2;  // covers block's q band [q0b, q0b+128)
  stageKV(0, 0);
  __syncthreads();
  int cur = 0;
  for (int t = 0; t < nkv; ++t) {
    const int kv0 = t * 64;
    if (t + 1 < nkv) stageKV(cur ^ 1, (t + 1) * 64);  // prefetch next tile

    // ---- QK^T (swapped): lane col = q, D-row = kv ----
    float sc[2][4][4];
    #pragma unroll
    for (int kvf = 0; kvf < 4; ++kvf) {
      int rr = kvf * 16 + lr;
      int sw = (rr & 7) << 4;
      const char* kbase = (const char*)&Kt[cur][0] + rr * 128;
      bf16x8 kf0 = *(const bf16x8*)(kbase + ((lg * 16) ^ sw));
      bf16x8 kf1 = *(const bf16x8*)(kbase + ((64 + lg * 16) ^ sw));
      #pragma unroll
      for (int q = 0; q < 2; ++q) {
        f32x4 a = vzero;
        a = MFMA16(kf0, qf[q][0], a);
        a = MFMA16(kf1, qf[q][1], a);
        #pragma unroll
        for (int r = 0; r < 4; ++r) sc[q][kvf][r] = a[r] * SCL;
      }
    }
    // causal mask only on diagonal-crossing tiles (wave-uniform check)
    if (kv0 + 63 > q0b + w * 32) {
      #pragma unroll
      for (int q = 0; q < 2; ++q) {
        int qrow = q ? qrow1 : qrow0;
        #pragma unroll
        for (int kvf = 0; kvf < 4; ++kvf)
          #pragma unroll
          for (int r = 0; r < 4; ++r) {
            int kv = kv0 + kvf * 16 + lg * 4 + r;
            if (kv > qrow) sc[q][kvf][r] = -3.0e9f;
          }
      }
    }

    // ---- online softmax per q-frag (row = q = lane&15), log2 domain ----
    #pragma unroll
    for (int q = 0; q < 2; ++q) {
      float tmax = -1e30f;
      #pragma unroll
      for (int kvf = 0; kvf < 4; ++kvf)
        #pragma unroll
        for (int r = 0; r < 4; ++r) tmax = fmaxf(tmax, sc[q][kvf][r]);
      tmax = fmaxf(tmax, __shfl_xor(tmax, 16));
      tmax = fmaxf(tmax, __shfl_xor(tmax, 32));
      // defer-max (T13): skip O/l rescale while tile max stays within THR=8
      if (!__all(tmax <= m_run[q] + 8.0f)) {
        float mnew = fmaxf(m_run[q], tmax);
        float alpha = exp2f(m_run[q] - mnew);
        l_run[q] *= alpha;
        #pragma unroll
        for (int d = 0; d < 4; ++d) oacc[q][d] *= alpha;
        m_run[q] = mnew;
      }
      float mq = m_run[q];
      float psum = 0.f;
      #pragma unroll
      for (int kvf = 0; kvf < 4; ++kvf)
        #pragma unroll
        for (int r = 0; r < 4; ++r) {
          float p = exp2f(sc[q][kvf][r] - mq);
          sc[q][kvf][r] = p;
          psum += p;
        }
      psum += __shfl_xor(psum, 16);
      psum += __shfl_xor(psum, 32);
      l_run[q] += psum;
      #pragma unroll
      for (int kvf = 0; kvf < 4; ++kvf) {
        bf16x4v pk;
        #pragma unroll
        for (int r = 0; r < 4; ++r) pk[r] = (bf16_t)sc[q][kvf][r];
        *(bf16x4v*)&P_lds[w][q * 16 + lr][kvf * 16 + lg * 4] = pk;
      }
    }
    // same-wave LDS RAW -> compiler lgkmcnt waits; no barrier needed

    // ---- PV: O^T[d][q] += V^T[d][kv] * P^T[kv][q] ----
    bf16x8 pf[2][2];
    #pragma unroll
    for (int q = 0; q < 2; ++q) {
      pf[q][0] = *(const bf16x8*)&P_lds[w][q * 16 + lr][lg * 8];
      pf[q][1] = *(const bf16x8*)&P_lds[w][q * 16 + lr][32 + lg * 8];
    }
    #pragma unroll
    for (int d = 0; d < 4; ++d) {
      int dl = d * 16 + lr;
      int sw = (dl & 7) << 4;
      const char* vbase = (const char*)&Vt[cur][0] + dl * 128;
      bf16x8 vf0 = *(const bf16x8*)(vbase + ((lg * 16) ^ sw));
      bf16x8 vf1 = *(const bf16x8*)(vbase + ((64 + lg * 16) ^ sw));
      #pragma unroll
      for (int q = 0; q < 2; ++q) {
        oacc[q][d] = MFMA16(vf0, pf[q][0], oacc[q][d]);
        oacc[q][d] = MFMA16(vf1, pf[q][1], oacc[q][d]);
      }
    }
    __syncthreads();  // drains prefetch + all waves done reading Kt/Vt[cur]
    cur ^= 1;
  }

  // ---- epilogue: merge heads into [B*S, D] bf16 ----
  const int b = bh >> 4, h = bh & 15;
  #pragma unroll
  for (int q = 0; q < 2; ++q) {
    float inv_l = 1.f / l_run[q];
    int qrow = q ? qrow1 : qrow0;
    #pragma unroll
    for (int d = 0; d < 4; ++d)
      #pragma unroll
      for (int r = 0; r < 4; ++r) {
        int dd = d * 16 + lg * 4 + r;
        attn_out[((size_t)(b * SS + qrow)) * DD + h * DH + dd] =
            (bf16_t)(oacc[q][d][r] * inv_l);
      }
  }
}

// ---------------- launcher ----------------
extern "C" void kernel_launch(void* const* d_in, const int* in_sizes, int n_in,
                              void* d_out, int out_size, void* d_ws, size_t ws_size,
                              hipStream_t stream) {
  const float* x = (const float*)d_in[0];
  const float* c_attn_w = (const float*)d_in[1];
  const float* c_attn_b = (const float*)d_in[2];
  const float* c_proj_w = (const float*)d_in[3];
  const float* c_proj_b = (const float*)d_in[4];

  float* out = (float*)d_out;                       // a: [B,S,D]
  float* present = out + (size_t)BB * SS * DD;      // present: [B,2,H,S,Dh]

  char* ws = (char*)d_ws;
  bf16_t* xb     = (bf16_t*)(ws + 0);               //  8.4 MB  x as bf16 [M,K]
  bf16_t* wqkvT  = (bf16_t*)(ws + 8388608);         //  6.3 MB  [3072,1024]
  bf16_t* wprojT = (bf16_t*)(ws + 14680064);        //  2.1 MB  [1024,1024]
  bf16_t* q_b    = (bf16_t*)(ws + 16777216);        //  8.4 MB  [B,H,S,64]
  bf16_t* k_b    = (bf16_t*)(ws + 25165824);        //  8.4 MB  [B,H,S,64]
  bf16_t* vt_b   = (bf16_t*)(ws + 33554432);        //  8.4 MB  [B,H,64,S]
  bf16_t* attn_o = (bf16_t*)(ws + 41943040);        //  8.4 MB  [M,D]

  // 1. x -> bf16
  cvt_f32_to_bf16<<<(MM * DD / 4 + 255) / 256, 256, 0, stream>>>(x, xb, MM * DD / 4);
  // 2. weight transposes
  transpose_f32_to_bf16<<<dim3(3 * DD / 32, DD / 32), dim3(32, 8), 0, stream>>>(
      c_attn_w, wqkvT, DD, 3 * DD);
  transpose_f32_to_bf16<<<dim3(DD / 32, DD / 32), dim3(32, 8), 0, stream>>>(
      c_proj_w, wprojT, DD, DD);
  // 3. QKV GEMM [4096,1024]x[1024,3072] with scatter epilogue
  gemm_bf16<0><<<dim3(3 * DD / 128, MM / 128), 256, 0, stream>>>(
      xb, wqkvT, c_attn_b, present, q_b, k_b, vt_b, MM, 3 * DD, DD);
  // 4. flash attention
  attn_fwd<<<dim3(SS / 128, BB * HH), 256, 0, stream>>>(q_b, k_b, vt_b, attn_o);
  // 5. output projection [4096,1024]x[1024,1024]
  gemm_bf16<1><<<dim3(DD / 128, MM / 128), 256, 0, stream>>>(
      attn_o, wprojT, c_proj_b, out, nullptr, nullptr, nullptr, MM, DD, DD);
}